// Round 11
// baseline (114.564 us; speedup 1.0000x reference)
//
#include <hip/hip_runtime.h>

// DCN-v2 low-rank mixture, L=3 E=4 D=512 R=64 B=16384.
// gate = softmax over size-1 axis == 1  -> G unused.
// xl' = x0 * (sum_e U_e tanh(C_e tanh(V_e^T xl)) + 4*bias) + xl, rows independent.
// R11: LDS-staged double-buffered weight stream (canonical GEMM pipeline).
//      Weights re-laid out K-major ([ks][colblk]) so each 32KB K-chunk is
//      contiguous; per chunk: global->reg->ds_write (8 VGPR fixed), B-frags
//      read from LDS. 8-chunk 2-phase pipeline for GEMM1 and GEMM3.
//      ROWS=64, 1024 thr, grid 256 (1 block/CU); x0 packed in 16 VGPRs
//      (captured in layer-0 epilogue). LDS = 64+32+2x32 = 160 KiB.

#define NL 3
#define NE 4
#define DD 512
#define RR 64
#define ROWS 64    // rows per block; grid = 16384/64 = 256 blocks
#define THREADS 1024

typedef __attribute__((ext_vector_type(8))) _Float16 f16x8;   // 8 fp16 = 4 VGPR
typedef __attribute__((ext_vector_type(4))) float f32x4;

#define MFMA(a, b, c) __builtin_amdgcn_mfma_f32_16x16x32_f16((a), (b), (c), 0, 0, 0)

__device__ __forceinline__ short f16b(float f) {
    _Float16 h = (_Float16)f;
    return __builtin_bit_cast(short, h);
}
__device__ __forceinline__ float f16tof(short s) {
    return (float)__builtin_bit_cast(_Float16, s);
}

__device__ __forceinline__ float ftanh(float x) {
    float t = __builtin_amdgcn_exp2f(x * 2.8853900817779268f);
    return 1.0f - 2.0f * __builtin_amdgcn_rcpf(t + 1.0f);
}

// ---- prep: fp16-cast + permute weights, K-MAJOR fragment-contiguous ----
// Fragment element (lane ln, j): col = 16*colblk + (ln&15), k = 32*kstep + (ln>>4)*8 + j.
// Vb3[l][ks(16)][colblk(16)][ln(64)][j(8)] = V[l][e=cb>>2][d=32ks+8(ln>>4)+j][r=16(cb&3)+(ln&15)]
//   -> 32KB chunk (2 ks x 16 colblk) is contiguous.
// Ub3[l][ks(8)][dblk(32)][ln][j]           = U[l][e=ks>>1][d=16dblk+(ln&15)][s=32(ks&1)+8(ln>>4)+j]
//   -> 32KB chunk (1 ks x 32 dblk) is contiguous.
// Ct2[l][e(4)][oc(4)][kc(2)][ln][j]        = C[l][e][r=32kc+8(ln>>4)+j][s=16oc+(ln&15)]
__global__ void prep_kernel(const float* __restrict__ U, const float* __restrict__ V,
                            const float* __restrict__ C,
                            short* __restrict__ Vb3, short* __restrict__ Ub3,
                            short* __restrict__ Ct2)
{
    int tid  = blockIdx.x * 256 + threadIdx.x;
    int nthr = gridDim.x * 256;
    for (int i = tid; i < NL * 131072; i += nthr) {
        int l = i >> 17; int q = i & 131071;
        int ks = q >> 13; int cb = (q >> 9) & 15;
        int ln = (q >> 3) & 63; int j = i & 7;
        int e = cb >> 2;
        int r = (cb & 3) * 16 + (ln & 15);
        int d = ks * 32 + (ln >> 4) * 8 + j;
        Vb3[i] = f16b(V[(((size_t)l * NE + e) * DD + d) * RR + r]);
    }
    for (int i = tid; i < NL * 131072; i += nthr) {
        int l = i >> 17; int q = i & 131071;
        int ks = q >> 14; int db = (q >> 9) & 31;
        int ln = (q >> 3) & 63; int j = i & 7;
        int e = ks >> 1;
        int d = db * 16 + (ln & 15);
        int s = (ks & 1) * 32 + (ln >> 4) * 8 + j;
        Ub3[i] = f16b(U[(((size_t)l * NE + e) * DD + d) * RR + s]);
    }
    for (int i = tid; i < NL * 16384; i += nthr) {
        int l = i >> 14; int q = i & 16383;
        int e = q >> 12; int rem = q & 4095;
        int oc = rem >> 10; int kc = (rem >> 9) & 1;
        int ln = (rem >> 3) & 63; int j = rem & 7;
        int r = kc * 32 + (ln >> 4) * 8 + j;
        int s = oc * 16 + (ln & 15);
        Ct2[i] = f16b(C[(((size_t)l * NE + e) * RR + r) * RR + s]);
    }
}

// XOR swizzle: breaks bank conflicts of row-major fp16 tiles on ds_read_b128
#define XLB_ADDR(row, colbyte) (((row) * (DD * 2)) + ((colbyte) ^ (((row) & 7) << 4)))
#define VB_ADDR(row, colbyte)  (((row) * (NE * RR * 2)) + ((colbyte) ^ (((row) & 7) << 4)))

__global__ __launch_bounds__(THREADS)
__attribute__((amdgpu_waves_per_eu(4, 4)))
void dcn_main(
    const float* __restrict__ x,
    const float* __restrict__ bias,
    const short* __restrict__ Vb3,
    const short* __restrict__ Ub3,
    const short* __restrict__ Ct2,
    float* __restrict__ out)
{
    __shared__ char xl_b[ROWS * DD * 2];        // 64 KiB fp16 xl carry tile (swizzled)
    __shared__ char sbuf[ROWS * NE * RR * 2];   // 32 KiB shared v/cv tile (swizzled)
    __shared__ char wst0[32768];                // 32 KiB weight stage ping
    __shared__ char wst1[32768];                // 32 KiB weight stage pong

    const int t   = threadIdx.x;
    const int w   = t >> 6;          // wave 0..15
    const int ln  = t & 63;
    const int l15 = ln & 15;
    const int kg  = ln >> 4;         // k-group 0..3
    const int row_base = blockIdx.x * ROWS;

    // ---- preamble: x (fp32, coalesced float4) -> fp16 xl_b ----
    #pragma unroll
    for (int q = 0; q < 8; ++q) {
        int p   = t + q * THREADS;
        int row = p >> 7;                 // 128 float4 per row
        int d4  = (p & 127) << 2;
        const float4 v4 = *(const float4*)(x + (size_t)(row_base + row) * DD + d4);
        short4 pk;
        pk.x = f16b(v4.x); pk.y = f16b(v4.y); pk.z = f16b(v4.z); pk.w = f16b(v4.w);
        *(short4*)(xl_b + XLB_ADDR(row, d4 * 2)) = pk;
    }
    // issue layer-0 GEMM1 chunk-0 stage loads (16B/thread x 2 segments)
    f16x8 sv0 = *(const f16x8*)(Vb3 + t * 8);
    f16x8 sv1 = *(const f16x8*)(Vb3 + 8192 + t * 8);
    __syncthreads();
    *(f16x8*)(wst0 + t * 16)         = sv0;
    *(f16x8*)(wst0 + 16384 + t * 16) = sv1;
    __syncthreads();                          // chunk 0 staged

    const int e2 = w >> 2;           // GEMM2 expert (4 waves/expert)
    const int q2 = w & 3;            // GEMM2 16-col quarter within expert

    unsigned x0p[2][4][2];           // x0 packed fp16x2, captured in layer-0 epilogue

    for (int layer = 0; layer < NL; ++layer) {
        const short* Vl = Vb3 + layer * 131072;
        const short* Ul = Ub3 + layer * 131072;
        const short* Cl = Ct2 + layer * 16384;
        const float* bl = bias + layer * DD;

        // ---- GEMM1: v = tanh(xl @ V); 8 chunks (K=64), 2-phase pipeline ----
        f32x4 acc1[4];
        #pragma unroll
        for (int mt = 0; mt < 4; ++mt) { f32x4 z = {0.f, 0.f, 0.f, 0.f}; acc1[mt] = z; }

        #pragma unroll
        for (int c = 0; c < 8; ++c) {
            f16x8 n0, n1;
            if (c < 7) {
                n0 = *(const f16x8*)(Vl + (c + 1) * 16384 + t * 8);
                n1 = *(const f16x8*)(Vl + (c + 1) * 16384 + 8192 + t * 8);
            }
            const char* rb = (c & 1) ? wst1 : wst0;
            #pragma unroll
            for (int k2 = 0; k2 < 2; ++k2) {
                f16x8 b = *(const f16x8*)(rb + (k2 * 16 + w) * 1024 + ln * 16);
                const int d0 = (c * 2 + k2) * 32 + kg * 8;
                #pragma unroll
                for (int mt = 0; mt < 4; ++mt) {
                    f16x8 a = *(const f16x8*)(xl_b + XLB_ADDR(l15 + 16 * mt, d0 * 2));
                    acc1[mt] = MFMA(a, b, acc1[mt]);
                }
            }
            if (c < 7) {
                char* wb = (c & 1) ? wst0 : wst1;
                *(f16x8*)(wb + t * 16)         = n0;
                *(f16x8*)(wb + 16384 + t * 16) = n1;
            }
            __syncthreads();
        }

        // v -> sbuf (wave owns v-cols [w*16, w*16+16))
        #pragma unroll
        for (int mt = 0; mt < 4; ++mt)
          #pragma unroll
          for (int r = 0; r < 4; ++r) {
              int row = mt * 16 + kg * 4 + r;
              int col = w * 16 + l15;
              *(short*)(sbuf + VB_ADDR(row, col * 2)) = f16b(ftanh(acc1[mt][r]));
          }
        // prefetch GEMM2's C b-frags (tiny, L2-hot)
        f16x8 pfc0 = *(const f16x8*)(Cl + ((e2 * 8 + q2 * 2 + 0) << 9) + ln * 8);
        f16x8 pfc1 = *(const f16x8*)(Cl + ((e2 * 8 + q2 * 2 + 1) << 9) + ln * 8);
        __syncthreads();   // v visible

        // ---- GEMM2: cv = tanh(v @ C_e) ----
        f32x4 acc2[4];
        #pragma unroll
        for (int mt = 0; mt < 4; ++mt) { f32x4 z = {0.f, 0.f, 0.f, 0.f}; acc2[mt] = z; }
        #pragma unroll
        for (int kc = 0; kc < 2; ++kc) {
            const int vcol = e2 * 64 + kc * 32 + kg * 8;
            f16x8 b = kc ? pfc1 : pfc0;
            #pragma unroll
            for (int mt = 0; mt < 4; ++mt) {
                f16x8 a = *(const f16x8*)(sbuf + VB_ADDR(l15 + 16 * mt, vcol * 2));
                acc2[mt] = MFMA(a, b, acc2[mt]);
            }
        }
        // issue GEMM3 chunk-0 stage loads; finish tanh in regs
        f16x8 su0 = *(const f16x8*)(Ul + t * 8);
        f16x8 su1 = *(const f16x8*)(Ul + 8192 + t * 8);
        float cvv[4][4];
        #pragma unroll
        for (int mt = 0; mt < 4; ++mt)
          #pragma unroll
          for (int r = 0; r < 4; ++r) cvv[mt][r] = ftanh(acc2[mt][r]);
        __syncthreads();   // all v-reads done before cv overwrites sbuf
        #pragma unroll
        for (int mt = 0; mt < 4; ++mt)
          #pragma unroll
          for (int r = 0; r < 4; ++r) {
              int row = mt * 16 + kg * 4 + r;
              int col = e2 * 64 + q2 * 16 + l15;
              *(short*)(sbuf + VB_ADDR(row, col * 2)) = f16b(cvv[mt][r]);
          }
        *(f16x8*)(wst0 + t * 16)         = su0;   // U chunk 0 -> ping
        *(f16x8*)(wst0 + 16384 + t * 16) = su1;
        __syncthreads();   // cv + U chunk 0 visible

        // ---- GEMM3: ucv = cv @ W; 8 chunks (k=32), 2-phase pipeline ----
        f32x4 acc3[4][2];
        #pragma unroll
        for (int mt = 0; mt < 4; ++mt)
          #pragma unroll
          for (int nt = 0; nt < 2; ++nt) { f32x4 z = {0.f, 0.f, 0.f, 0.f}; acc3[mt][nt] = z; }

        #pragma unroll
        for (int c = 0; c < 8; ++c) {
            f16x8 n0, n1;
            if (c < 7) {
                n0 = *(const f16x8*)(Ul + (c + 1) * 16384 + t * 8);
                n1 = *(const f16x8*)(Ul + (c + 1) * 16384 + 8192 + t * 8);
            }
            const char* rb = (c & 1) ? wst1 : wst0;
            f16x8 b0 = *(const f16x8*)(rb + (w * 2 + 0) * 1024 + ln * 16);
            f16x8 b1 = *(const f16x8*)(rb + (w * 2 + 1) * 1024 + ln * 16);
            const int k0 = c * 32 + kg * 8;
            #pragma unroll
            for (int mt = 0; mt < 4; ++mt) {
                f16x8 a = *(const f16x8*)(sbuf + VB_ADDR(l15 + 16 * mt, k0 * 2));
                acc3[mt][0] = MFMA(a, b0, acc3[mt][0]);
                acc3[mt][1] = MFMA(a, b1, acc3[mt][1]);
            }
            if (c < 7) {
                char* wb = (c & 1) ? wst0 : wst1;
                *(f16x8*)(wb + t * 16)         = n0;
                *(f16x8*)(wb + 16384 + t * 16) = n1;
            }
            __syncthreads();
        }

        // ---- epilogue (pure LDS): xl' = x0*(ucv + 4*bias) + xl_old ----
        // layer 0: x0 == xl_old, captured packed into x0p (16 VGPR, persistent)
        #pragma unroll
        for (int nt = 0; nt < 2; ++nt) {
            const int col = w * 32 + nt * 16 + l15;
            const float bv = 4.0f * bl[col];
            #pragma unroll
            for (int mt = 0; mt < 4; ++mt) {
                const int row0 = mt * 16 + kg * 4;
                #pragma unroll
                for (int pr = 0; pr < 2; ++pr) {
                    short h0 = *(const short*)(xl_b + XLB_ADDR(row0 + pr * 2 + 0, col * 2));
                    short h1 = *(const short*)(xl_b + XLB_ADDR(row0 + pr * 2 + 1, col * 2));
                    float xo0 = f16tof(h0), xo1 = f16tof(h1);
                    float x00, x01;
                    if (layer == 0) {
                        x00 = xo0; x01 = xo1;
                        x0p[nt][mt][pr] = (unsigned)(unsigned short)h0
                                        | ((unsigned)(unsigned short)h1 << 16);
                    } else {
                        unsigned pk = x0p[nt][mt][pr];
                        x00 = f16tof((short)(pk & 0xffffu));
                        x01 = f16tof((short)(pk >> 16));
                    }
                    float nn0 = x00 * (acc3[mt][nt][pr * 2 + 0] + bv) + xo0;
                    float nn1 = x01 * (acc3[mt][nt][pr * 2 + 1] + bv) + xo1;
                    *(short*)(xl_b + XLB_ADDR(row0 + pr * 2 + 0, col * 2)) = f16b(nn0);
                    *(short*)(xl_b + XLB_ADDR(row0 + pr * 2 + 1, col * 2)) = f16b(nn1);
                }
            }
        }
        // issue next layer's GEMM1 chunk-0 loads before the barrier
        f16x8 nv0, nv1;
        if (layer < NL - 1) {
            nv0 = *(const f16x8*)(Vl + 131072 + t * 8);
            nv1 = *(const f16x8*)(Vl + 131072 + 8192 + t * 8);
        }
        __syncthreads();   // xl' visible; all wst reads done
        if (layer < NL - 1) {
            *(f16x8*)(wst0 + t * 16)         = nv0;
            *(f16x8*)(wst0 + 16384 + t * 16) = nv1;
            __syncthreads();   // next V chunk 0 staged
        }
    }

    // ---- final: coalesced float4 store of xl_b (fp16 -> fp32) ----
    #pragma unroll
    for (int q = 0; q < 8; ++q) {
        int p   = t + q * THREADS;
        int row = p >> 7;
        int d4  = (p & 127) << 2;
        short4 pk = *(const short4*)(xl_b + XLB_ADDR(row, d4 * 2));
        float4 v4;
        v4.x = f16tof(pk.x); v4.y = f16tof(pk.y); v4.z = f16tof(pk.z); v4.w = f16tof(pk.w);
        *(float4*)(out + (size_t)(row_base + row) * DD + d4) = v4;
    }
}

extern "C" void kernel_launch(void* const* d_in, const int* in_sizes, int n_in,
                              void* d_out, int out_size, void* d_ws, size_t ws_size,
                              hipStream_t stream) {
    const float* x    = (const float*)d_in[0];
    const float* U    = (const float*)d_in[1];
    const float* V    = (const float*)d_in[2];
    const float* C    = (const float*)d_in[3];
    // d_in[4] = G : unused (gate == 1 exactly)
    const float* bias = (const float*)d_in[5];
    float* out = (float*)d_out;

    short* Vb3 = (short*)d_ws;                 // 786432 B
    short* Ub3 = Vb3 + NL * 131072;            // 786432 B
    short* Ct2 = Ub3 + NL * 131072;            // 98304 B  (total ~1.6 MiB)

    prep_kernel<<<dim3(256), dim3(256), 0, stream>>>(U, V, C, Vb3, Ub3, Ct2);
    dcn_main<<<dim3(16384 / ROWS), dim3(THREADS), 0, stream>>>(x, bias, Vb3, Ub3, Ct2, out);
}

// Round 12
// 74.291 us; speedup vs baseline: 1.5421x; 1.5421x over previous
//
#include <hip/hip_runtime.h>

// DCN-v2 low-rank mixture, L=3 E=4 D=512 R=64 B=16384.
// gate = softmax over size-1 axis == 1  -> G unused.
// xl' = x0 * (sum_e U_e tanh(C_e tanh(V_e^T xl)) + 4*bias) + xl, rows independent.
// R12: R10 geometry (ROWS=64, 1024 thr, grid 256 = 1 block/CU, halved weight
//      stream) engineered to fit the 64-VGPR tier the allocator insists on:
//      no cross-barrier prefetch regs, GEMM3 split into two nt-halves with
//      fused per-half epilogue (peak live ~45 VGPR). x0 in LDS.
//      LDS = 64K xl + 64K x0 + 32K sbuf = 160 KiB.

#define NL 3
#define NE 4
#define DD 512
#define RR 64
#define ROWS 64    // rows per block; grid = 16384/64 = 256 blocks
#define THREADS 1024

typedef __attribute__((ext_vector_type(8))) _Float16 f16x8;   // 8 fp16 = 4 VGPR
typedef __attribute__((ext_vector_type(4))) float f32x4;

#define MFMA(a, b, c) __builtin_amdgcn_mfma_f32_16x16x32_f16((a), (b), (c), 0, 0, 0)

__device__ __forceinline__ short f16b(float f) {
    _Float16 h = (_Float16)f;
    return __builtin_bit_cast(short, h);
}
__device__ __forceinline__ float f16tof(short s) {
    return (float)__builtin_bit_cast(_Float16, s);
}

__device__ __forceinline__ float ftanh(float x) {
    float t = __builtin_amdgcn_exp2f(x * 2.8853900817779268f);
    return 1.0f - 2.0f * __builtin_amdgcn_rcpf(t + 1.0f);
}

// ---- prep: fp16-cast + permute weights into MFMA-fragment-contiguous order ----
// Fragment element (lane ln, j): col = 16*colblk + (ln&15), k = 32*kstep + (ln>>4)*8 + j.
// Vb2[l][colblk(16)][ks(16)][ln(64)][j(8)]  = V[l][e=colblk>>2][d=32ks+8(ln>>4)+j][r=16(colblk&3)+(ln&15)]
// Ub2[l][dblk(32)][ks(8)][ln][j]            = U[l][e=ks>>1][d=16dblk+(ln&15)][s=32(ks&1)+8(ln>>4)+j]
// Ct2[l][e(4)][oc(4)][kc(2)][ln][j]         = C[l][e][r=32kc+8(ln>>4)+j][s=16oc+(ln&15)]
__global__ void prep_kernel(const float* __restrict__ U, const float* __restrict__ V,
                            const float* __restrict__ C,
                            short* __restrict__ Vb2, short* __restrict__ Ub2,
                            short* __restrict__ Ct2)
{
    int tid  = blockIdx.x * 256 + threadIdx.x;
    int nthr = gridDim.x * 256;
    for (int i = tid; i < NL * 131072; i += nthr) {
        int l = i >> 17; int q = i & 131071;
        int colblk = q >> 13; int rem = q & 8191;
        int ks = rem >> 9; int ln = (rem >> 3) & 63; int j = rem & 7;
        int e = colblk >> 2;
        int r = (colblk & 3) * 16 + (ln & 15);
        int d = ks * 32 + (ln >> 4) * 8 + j;
        Vb2[i] = f16b(V[(((size_t)l * NE + e) * DD + d) * RR + r]);
    }
    for (int i = tid; i < NL * 131072; i += nthr) {
        int l = i >> 17; int q = i & 131071;
        int dblk = q >> 12; int rem = q & 4095;
        int ks = rem >> 9; int ln = (rem >> 3) & 63; int j = rem & 7;
        int e = ks >> 1;
        int d = dblk * 16 + (ln & 15);
        int s = (ks & 1) * 32 + (ln >> 4) * 8 + j;
        Ub2[i] = f16b(U[(((size_t)l * NE + e) * DD + d) * RR + s]);
    }
    for (int i = tid; i < NL * 16384; i += nthr) {
        int l = i >> 14; int q = i & 16383;
        int e = q >> 12; int rem = q & 4095;
        int oc = rem >> 10; int kc = (rem >> 9) & 1;
        int ln = (rem >> 3) & 63; int j = rem & 7;
        int r = kc * 32 + (ln >> 4) * 8 + j;
        int s = oc * 16 + (ln & 15);
        Ct2[i] = f16b(C[(((size_t)l * NE + e) * RR + r) * RR + s]);
    }
}

// XOR swizzle: breaks bank conflicts of row-major fp16 tiles on ds_read_b128
#define XLB_ADDR(row, colbyte) (((row) * (DD * 2)) + ((colbyte) ^ (((row) & 7) << 4)))
#define VB_ADDR(row, colbyte)  (((row) * (NE * RR * 2)) + ((colbyte) ^ (((row) & 7) << 4)))

__global__ __launch_bounds__(THREADS) void dcn_main(
    const float* __restrict__ x,
    const float* __restrict__ bias,
    const short* __restrict__ Vb2,
    const short* __restrict__ Ub2,
    const short* __restrict__ Ct2,
    float* __restrict__ out)
{
    __shared__ char xl_b[ROWS * DD * 2];        // 64 KiB fp16 xl carry tile (swizzled)
    __shared__ char x0_b[ROWS * DD * 2];        // 64 KiB fp16 x0 tile (swizzled)
    __shared__ char sbuf[ROWS * NE * RR * 2];   // 32 KiB shared v/cv tile (swizzled)

    const int t   = threadIdx.x;
    const int w   = t >> 6;          // wave 0..15
    const int ln  = t & 63;
    const int l15 = ln & 15;
    const int kg  = ln >> 4;         // k-group 0..3
    const int row_base = blockIdx.x * ROWS;

    // ---- preamble: x (fp32, coalesced float4) -> fp16 xl_b AND x0_b ----
    #pragma unroll
    for (int q = 0; q < 8; ++q) {
        int p   = t + q * THREADS;
        int row = p >> 7;                 // 128 float4 per row
        int d4  = (p & 127) << 2;
        const float4 v4 = *(const float4*)(x + (size_t)(row_base + row) * DD + d4);
        short4 pk;
        pk.x = f16b(v4.x); pk.y = f16b(v4.y); pk.z = f16b(v4.z); pk.w = f16b(v4.w);
        *(short4*)(xl_b + XLB_ADDR(row, d4 * 2)) = pk;
        *(short4*)(x0_b + XLB_ADDR(row, d4 * 2)) = pk;
    }
    __syncthreads();

    const int e2 = w >> 2;           // GEMM2 expert for this wave (4 waves/expert)
    const int q2 = w & 3;            // GEMM2 16-col quarter within expert

    #pragma unroll
    for (int layer = 0; layer < NL; ++layer) {
        const short* Vl = Vb2 + layer * 131072;
        const short* Ul = Ub2 + layer * 131072;
        const short* Cl = Ct2 + layer * 16384;
        const float* bl = bias + layer * DD;

        // ---- GEMM1: v = tanh(xl @ V); wave owns v-cols [w*16, w*16+16) (1 colblk) ----
        f32x4 acc1[4];
        #pragma unroll
        for (int mt = 0; mt < 4; ++mt) { f32x4 z = {0.f, 0.f, 0.f, 0.f}; acc1[mt] = z; }

        #pragma unroll 2
        for (int ks = 0; ks < 16; ++ks) {
            const int d0 = ks * 32 + kg * 8;
            f16x8 b = *(const f16x8*)(Vl + ((w * 16 + ks) << 9) + ln * 8);
            #pragma unroll
            for (int mt = 0; mt < 4; ++mt) {
                f16x8 a = *(const f16x8*)(xl_b + XLB_ADDR(l15 + 16 * mt, d0 * 2));
                acc1[mt] = MFMA(a, b, acc1[mt]);
            }
        }
        #pragma unroll
        for (int mt = 0; mt < 4; ++mt)
          #pragma unroll
          for (int r = 0; r < 4; ++r) {
              int row = mt * 16 + kg * 4 + r;
              int col = w * 16 + l15;
              *(short*)(sbuf + VB_ADDR(row, col * 2)) = f16b(ftanh(acc1[mt][r]));
          }
        // load GEMM2's C b-frags (tiny, L2-hot) before the barrier
        f16x8 pfc0 = *(const f16x8*)(Cl + ((e2 * 8 + q2 * 2 + 0) << 9) + ln * 8);
        f16x8 pfc1 = *(const f16x8*)(Cl + ((e2 * 8 + q2 * 2 + 1) << 9) + ln * 8);
        __syncthreads();   // v visible

        // ---- GEMM2: cv = tanh(v @ C_e); 4 waves per expert, 16 cols each ----
        f32x4 acc2[4];
        #pragma unroll
        for (int mt = 0; mt < 4; ++mt) { f32x4 z = {0.f, 0.f, 0.f, 0.f}; acc2[mt] = z; }

        #pragma unroll
        for (int kc = 0; kc < 2; ++kc) {
            const int vcol = e2 * 64 + kc * 32 + kg * 8;
            f16x8 b = kc ? pfc1 : pfc0;
            #pragma unroll
            for (int mt = 0; mt < 4; ++mt) {
                f16x8 a = *(const f16x8*)(sbuf + VB_ADDR(l15 + 16 * mt, vcol * 2));
                acc2[mt] = MFMA(a, b, acc2[mt]);
            }
        }
        // finish tanh in regs; all v-reads must complete before cv overwrites sbuf
        float cvv[4][4];
        #pragma unroll
        for (int mt = 0; mt < 4; ++mt)
          #pragma unroll
          for (int r = 0; r < 4; ++r) cvv[mt][r] = ftanh(acc2[mt][r]);
        __syncthreads();
        #pragma unroll
        for (int mt = 0; mt < 4; ++mt)
          #pragma unroll
          for (int r = 0; r < 4; ++r) {
              int row = mt * 16 + kg * 4 + r;
              int col = e2 * 64 + q2 * 16 + l15;
              *(short*)(sbuf + VB_ADDR(row, col * 2)) = f16b(cvv[mt][r]);
          }
        __syncthreads();   // cv visible

        // ---- GEMM3 in two nt-halves, epilogue fused per half (acc stays <=16) ----
        #pragma unroll
        for (int h = 0; h < 2; ++h) {
            f32x4 acc3[4];
            #pragma unroll
            for (int mt = 0; mt < 4; ++mt) { f32x4 z = {0.f, 0.f, 0.f, 0.f}; acc3[mt] = z; }

            #pragma unroll 2
            for (int ks = 0; ks < 8; ++ks) {
                const int k0 = ks * 32 + kg * 8;
                f16x8 b = *(const f16x8*)(Ul + (((w * 2 + h) * 8 + ks) << 9) + ln * 8);
                #pragma unroll
                for (int mt = 0; mt < 4; ++mt) {
                    f16x8 a = *(const f16x8*)(sbuf + VB_ADDR(l15 + 16 * mt, k0 * 2));
                    acc3[mt] = MFMA(a, b, acc3[mt]);
                }
            }
            // epilogue for this half (pure LDS): xl' = x0*(ucv + 4*bias) + xl_old
            const int col = w * 32 + h * 16 + l15;
            const float bv = 4.0f * bl[col];
            #pragma unroll
            for (int mt = 0; mt < 4; ++mt) {
                const int row0 = mt * 16 + kg * 4;
                #pragma unroll
                for (int r = 0; r < 4; ++r) {
                    float xo = f16tof(*(const short*)(xl_b + XLB_ADDR(row0 + r, col * 2)));
                    float x0 = f16tof(*(const short*)(x0_b + XLB_ADDR(row0 + r, col * 2)));
                    float n  = x0 * (acc3[mt][r] + bv) + xo;
                    *(short*)(xl_b + XLB_ADDR(row0 + r, col * 2)) = f16b(n);
                }
            }
        }
        __syncthreads();   // xl' visible to next GEMM1 / final copy
    }

    // ---- final: coalesced float4 store of xl_b (fp16 -> fp32) ----
    #pragma unroll
    for (int q = 0; q < 8; ++q) {
        int p   = t + q * THREADS;
        int row = p >> 7;
        int d4  = (p & 127) << 2;
        short4 pk = *(const short4*)(xl_b + XLB_ADDR(row, d4 * 2));
        float4 v4;
        v4.x = f16tof(pk.x); v4.y = f16tof(pk.y); v4.z = f16tof(pk.z); v4.w = f16tof(pk.w);
        *(float4*)(out + (size_t)(row_base + row) * DD + d4) = v4;
    }
}

extern "C" void kernel_launch(void* const* d_in, const int* in_sizes, int n_in,
                              void* d_out, int out_size, void* d_ws, size_t ws_size,
                              hipStream_t stream) {
    const float* x    = (const float*)d_in[0];
    const float* U    = (const float*)d_in[1];
    const float* V    = (const float*)d_in[2];
    const float* C    = (const float*)d_in[3];
    // d_in[4] = G : unused (gate == 1 exactly)
    const float* bias = (const float*)d_in[5];
    float* out = (float*)d_out;

    short* Vb2 = (short*)d_ws;                 // 786432 B
    short* Ub2 = Vb2 + NL * 131072;            // 786432 B
    short* Ct2 = Ub2 + NL * 131072;            // 98304 B  (total ~1.6 MiB)

    prep_kernel<<<dim3(256), dim3(256), 0, stream>>>(U, V, C, Vb2, Ub2, Ct2);
    dcn_main<<<dim3(16384 / ROWS), dim3(THREADS), 0, stream>>>(x, bias, Vb2, Ub2, Ct2, out);
}

// Round 13
// 72.645 us; speedup vs baseline: 1.5770x; 1.0227x over previous
//
#include <hip/hip_runtime.h>

// DCN-v2 low-rank mixture, L=3 E=4 D=512 R=64 B=16384.
// gate = softmax over size-1 axis == 1  -> G unused.
// xl' = x0 * (sum_e U_e tanh(C_e tanh(V_e^T xl)) + 4*bias) + xl, rows independent.
// R13: = R12 + __launch_bounds__(1024, 4) (min 4 waves/EU -> 128-VGPR tier;
//      a 1024-thr block needs exactly 4 waves/EU, so occupancy is unchanged)
//      + unroll 4 on GEMM1/GEMM3 k-loops (4 weight-loads in flight/wave).
//      LDS = 64K xl + 64K x0 + 32K sbuf = 160 KiB, grid 256 (1 block/CU).

#define NL 3
#define NE 4
#define DD 512
#define RR 64
#define ROWS 64    // rows per block; grid = 16384/64 = 256 blocks
#define THREADS 1024

typedef __attribute__((ext_vector_type(8))) _Float16 f16x8;   // 8 fp16 = 4 VGPR
typedef __attribute__((ext_vector_type(4))) float f32x4;

#define MFMA(a, b, c) __builtin_amdgcn_mfma_f32_16x16x32_f16((a), (b), (c), 0, 0, 0)

__device__ __forceinline__ short f16b(float f) {
    _Float16 h = (_Float16)f;
    return __builtin_bit_cast(short, h);
}
__device__ __forceinline__ float f16tof(short s) {
    return (float)__builtin_bit_cast(_Float16, s);
}

__device__ __forceinline__ float ftanh(float x) {
    float t = __builtin_amdgcn_exp2f(x * 2.8853900817779268f);
    return 1.0f - 2.0f * __builtin_amdgcn_rcpf(t + 1.0f);
}

// ---- prep: fp16-cast + permute weights into MFMA-fragment-contiguous order ----
// Fragment element (lane ln, j): col = 16*colblk + (ln&15), k = 32*kstep + (ln>>4)*8 + j.
// Vb2[l][colblk(16)][ks(16)][ln(64)][j(8)]  = V[l][e=colblk>>2][d=32ks+8(ln>>4)+j][r=16(colblk&3)+(ln&15)]
// Ub2[l][dblk(32)][ks(8)][ln][j]            = U[l][e=ks>>1][d=16dblk+(ln&15)][s=32(ks&1)+8(ln>>4)+j]
// Ct2[l][e(4)][oc(4)][kc(2)][ln][j]         = C[l][e][r=32kc+8(ln>>4)+j][s=16oc+(ln&15)]
__global__ void prep_kernel(const float* __restrict__ U, const float* __restrict__ V,
                            const float* __restrict__ C,
                            short* __restrict__ Vb2, short* __restrict__ Ub2,
                            short* __restrict__ Ct2)
{
    int tid  = blockIdx.x * 256 + threadIdx.x;
    int nthr = gridDim.x * 256;
    for (int i = tid; i < NL * 131072; i += nthr) {
        int l = i >> 17; int q = i & 131071;
        int colblk = q >> 13; int rem = q & 8191;
        int ks = rem >> 9; int ln = (rem >> 3) & 63; int j = rem & 7;
        int e = colblk >> 2;
        int r = (colblk & 3) * 16 + (ln & 15);
        int d = ks * 32 + (ln >> 4) * 8 + j;
        Vb2[i] = f16b(V[(((size_t)l * NE + e) * DD + d) * RR + r]);
    }
    for (int i = tid; i < NL * 131072; i += nthr) {
        int l = i >> 17; int q = i & 131071;
        int dblk = q >> 12; int rem = q & 4095;
        int ks = rem >> 9; int ln = (rem >> 3) & 63; int j = rem & 7;
        int e = ks >> 1;
        int d = dblk * 16 + (ln & 15);
        int s = (ks & 1) * 32 + (ln >> 4) * 8 + j;
        Ub2[i] = f16b(U[(((size_t)l * NE + e) * DD + d) * RR + s]);
    }
    for (int i = tid; i < NL * 16384; i += nthr) {
        int l = i >> 14; int q = i & 16383;
        int e = q >> 12; int rem = q & 4095;
        int oc = rem >> 10; int kc = (rem >> 9) & 1;
        int ln = (rem >> 3) & 63; int j = rem & 7;
        int r = kc * 32 + (ln >> 4) * 8 + j;
        int s = oc * 16 + (ln & 15);
        Ct2[i] = f16b(C[(((size_t)l * NE + e) * RR + r) * RR + s]);
    }
}

// XOR swizzle: breaks bank conflicts of row-major fp16 tiles on ds_read_b128
#define XLB_ADDR(row, colbyte) (((row) * (DD * 2)) + ((colbyte) ^ (((row) & 7) << 4)))
#define VB_ADDR(row, colbyte)  (((row) * (NE * RR * 2)) + ((colbyte) ^ (((row) & 7) << 4)))

__global__ __launch_bounds__(THREADS, 4) void dcn_main(
    const float* __restrict__ x,
    const float* __restrict__ bias,
    const short* __restrict__ Vb2,
    const short* __restrict__ Ub2,
    const short* __restrict__ Ct2,
    float* __restrict__ out)
{
    __shared__ char xl_b[ROWS * DD * 2];        // 64 KiB fp16 xl carry tile (swizzled)
    __shared__ char x0_b[ROWS * DD * 2];        // 64 KiB fp16 x0 tile (swizzled)
    __shared__ char sbuf[ROWS * NE * RR * 2];   // 32 KiB shared v/cv tile (swizzled)

    const int t   = threadIdx.x;
    const int w   = t >> 6;          // wave 0..15
    const int ln  = t & 63;
    const int l15 = ln & 15;
    const int kg  = ln >> 4;         // k-group 0..3
    const int row_base = blockIdx.x * ROWS;

    // ---- preamble: x (fp32, coalesced float4) -> fp16 xl_b AND x0_b ----
    #pragma unroll
    for (int q = 0; q < 8; ++q) {
        int p   = t + q * THREADS;
        int row = p >> 7;                 // 128 float4 per row
        int d4  = (p & 127) << 2;
        const float4 v4 = *(const float4*)(x + (size_t)(row_base + row) * DD + d4);
        short4 pk;
        pk.x = f16b(v4.x); pk.y = f16b(v4.y); pk.z = f16b(v4.z); pk.w = f16b(v4.w);
        *(short4*)(xl_b + XLB_ADDR(row, d4 * 2)) = pk;
        *(short4*)(x0_b + XLB_ADDR(row, d4 * 2)) = pk;
    }
    __syncthreads();

    const int e2 = w >> 2;           // GEMM2 expert for this wave (4 waves/expert)
    const int q2 = w & 3;            // GEMM2 16-col quarter within expert

    #pragma unroll
    for (int layer = 0; layer < NL; ++layer) {
        const short* Vl = Vb2 + layer * 131072;
        const short* Ul = Ub2 + layer * 131072;
        const short* Cl = Ct2 + layer * 16384;
        const float* bl = bias + layer * DD;

        // ---- GEMM1: v = tanh(xl @ V); wave owns v-cols [w*16, w*16+16) (1 colblk) ----
        f32x4 acc1[4];
        #pragma unroll
        for (int mt = 0; mt < 4; ++mt) { f32x4 z = {0.f, 0.f, 0.f, 0.f}; acc1[mt] = z; }

        #pragma unroll 4
        for (int ks = 0; ks < 16; ++ks) {
            const int d0 = ks * 32 + kg * 8;
            f16x8 b = *(const f16x8*)(Vl + ((w * 16 + ks) << 9) + ln * 8);
            #pragma unroll
            for (int mt = 0; mt < 4; ++mt) {
                f16x8 a = *(const f16x8*)(xl_b + XLB_ADDR(l15 + 16 * mt, d0 * 2));
                acc1[mt] = MFMA(a, b, acc1[mt]);
            }
        }
        #pragma unroll
        for (int mt = 0; mt < 4; ++mt)
          #pragma unroll
          for (int r = 0; r < 4; ++r) {
              int row = mt * 16 + kg * 4 + r;
              int col = w * 16 + l15;
              *(short*)(sbuf + VB_ADDR(row, col * 2)) = f16b(ftanh(acc1[mt][r]));
          }
        // load GEMM2's C b-frags (tiny, L2-hot) before the barrier
        f16x8 pfc0 = *(const f16x8*)(Cl + ((e2 * 8 + q2 * 2 + 0) << 9) + ln * 8);
        f16x8 pfc1 = *(const f16x8*)(Cl + ((e2 * 8 + q2 * 2 + 1) << 9) + ln * 8);
        __syncthreads();   // v visible

        // ---- GEMM2: cv = tanh(v @ C_e); 4 waves per expert, 16 cols each ----
        f32x4 acc2[4];
        #pragma unroll
        for (int mt = 0; mt < 4; ++mt) { f32x4 z = {0.f, 0.f, 0.f, 0.f}; acc2[mt] = z; }

        #pragma unroll
        for (int kc = 0; kc < 2; ++kc) {
            const int vcol = e2 * 64 + kc * 32 + kg * 8;
            f16x8 b = kc ? pfc1 : pfc0;
            #pragma unroll
            for (int mt = 0; mt < 4; ++mt) {
                f16x8 a = *(const f16x8*)(sbuf + VB_ADDR(l15 + 16 * mt, vcol * 2));
                acc2[mt] = MFMA(a, b, acc2[mt]);
            }
        }
        // finish tanh in regs; all v-reads must complete before cv overwrites sbuf
        float cvv[4][4];
        #pragma unroll
        for (int mt = 0; mt < 4; ++mt)
          #pragma unroll
          for (int r = 0; r < 4; ++r) cvv[mt][r] = ftanh(acc2[mt][r]);
        __syncthreads();
        #pragma unroll
        for (int mt = 0; mt < 4; ++mt)
          #pragma unroll
          for (int r = 0; r < 4; ++r) {
              int row = mt * 16 + kg * 4 + r;
              int col = e2 * 64 + q2 * 16 + l15;
              *(short*)(sbuf + VB_ADDR(row, col * 2)) = f16b(cvv[mt][r]);
          }
        __syncthreads();   // cv visible

        // ---- GEMM3 in two nt-halves, epilogue fused per half (acc stays <=16) ----
        #pragma unroll
        for (int h = 0; h < 2; ++h) {
            f32x4 acc3[4];
            #pragma unroll
            for (int mt = 0; mt < 4; ++mt) { f32x4 z = {0.f, 0.f, 0.f, 0.f}; acc3[mt] = z; }

            #pragma unroll 4
            for (int ks = 0; ks < 8; ++ks) {
                const int k0 = ks * 32 + kg * 8;
                f16x8 b = *(const f16x8*)(Ul + (((w * 2 + h) * 8 + ks) << 9) + ln * 8);
                #pragma unroll
                for (int mt = 0; mt < 4; ++mt) {
                    f16x8 a = *(const f16x8*)(sbuf + VB_ADDR(l15 + 16 * mt, k0 * 2));
                    acc3[mt] = MFMA(a, b, acc3[mt]);
                }
            }
            // epilogue for this half (pure LDS): xl' = x0*(ucv + 4*bias) + xl_old
            const int col = w * 32 + h * 16 + l15;
            const float bv = 4.0f * bl[col];
            #pragma unroll
            for (int mt = 0; mt < 4; ++mt) {
                const int row0 = mt * 16 + kg * 4;
                #pragma unroll
                for (int r = 0; r < 4; ++r) {
                    float xo = f16tof(*(const short*)(xl_b + XLB_ADDR(row0 + r, col * 2)));
                    float x0 = f16tof(*(const short*)(x0_b + XLB_ADDR(row0 + r, col * 2)));
                    float n  = x0 * (acc3[mt][r] + bv) + xo;
                    *(short*)(xl_b + XLB_ADDR(row0 + r, col * 2)) = f16b(n);
                }
            }
        }
        __syncthreads();   // xl' visible to next GEMM1 / final copy
    }

    // ---- final: coalesced float4 store of xl_b (fp16 -> fp32) ----
    #pragma unroll
    for (int q = 0; q < 8; ++q) {
        int p   = t + q * THREADS;
        int row = p >> 7;
        int d4  = (p & 127) << 2;
        short4 pk = *(const short4*)(xl_b + XLB_ADDR(row, d4 * 2));
        float4 v4;
        v4.x = f16tof(pk.x); v4.y = f16tof(pk.y); v4.z = f16tof(pk.z); v4.w = f16tof(pk.w);
        *(float4*)(out + (size_t)(row_base + row) * DD + d4) = v4;
    }
}

extern "C" void kernel_launch(void* const* d_in, const int* in_sizes, int n_in,
                              void* d_out, int out_size, void* d_ws, size_t ws_size,
                              hipStream_t stream) {
    const float* x    = (const float*)d_in[0];
    const float* U    = (const float*)d_in[1];
    const float* V    = (const float*)d_in[2];
    const float* C    = (const float*)d_in[3];
    // d_in[4] = G : unused (gate == 1 exactly)
    const float* bias = (const float*)d_in[5];
    float* out = (float*)d_out;

    short* Vb2 = (short*)d_ws;                 // 786432 B
    short* Ub2 = Vb2 + NL * 131072;            // 786432 B
    short* Ct2 = Ub2 + NL * 131072;            // 98304 B  (total ~1.6 MiB)

    prep_kernel<<<dim3(256), dim3(256), 0, stream>>>(U, V, C, Vb2, Ub2, Ct2);
    dcn_main<<<dim3(16384 / ROWS), dim3(THREADS), 0, stream>>>(x, bias, Vb2, Ub2, Ct2, out);
}